// Round 5
// baseline (1090.131 us; speedup 1.0000x reference)
//
#include <hip/hip_runtime.h>

// ---------------- problem constants ----------------
#define BQ   8
#define SQ   1569
#define BS   12552      // BQ*SQ
#define DM   768
#define NH   12
#define DH   64
#define TT   8
#define PP   196
#define D4   3072
#define QKVN 2304
#define CCH  24         // CLS split-K chunks
#define CKEY 66         // keys per chunk (24*66 = 1584 >= 1569)
#define MB_PAD 104      // 99 m-blocks padded to multiple of 8 for XCD-stable swizzle

typedef _Float16 f16;
typedef _Float16 f16x8 __attribute__((ext_vector_type(8)));
typedef float    f32x4 __attribute__((ext_vector_type(4)));
typedef unsigned long long u64;

#define AS1 __attribute__((address_space(1)))
#define AS3 __attribute__((address_space(3)))

#define Y_OFF    0ULL
#define QKV_OFF  19279872ULL
#define CTX_OFF  77119488ULL
#define H_OFF    19279872ULL
#define W_OFF    96399360ULL

// ---------------- LayerNorm (wave per row) ----------------
__global__ __launch_bounds__(256) void ln_kernel(const float* __restrict__ x,
                                                 const float* __restrict__ g,
                                                 const float* __restrict__ bta,
                                                 f16* __restrict__ y) {
    int row = blockIdx.x * 4 + (threadIdx.x >> 6);
    int lane = threadIdx.x & 63;
    if (row >= BS) return;
    const float* xr = x + (u64)row * DM;
    float v[12];
    float s = 0.f, s2 = 0.f;
#pragma unroll
    for (int i = 0; i < 12; i++) { v[i] = xr[lane + i * 64]; s += v[i]; s2 += v[i] * v[i]; }
#pragma unroll
    for (int m = 1; m < 64; m <<= 1) { s += __shfl_xor(s, m, 64); s2 += __shfl_xor(s2, m, 64); }
    float mean = s * (1.f / 768.f);
    float var  = s2 * (1.f / 768.f) - mean * mean;
    float rstd = rsqrtf(var + 1e-12f);
    f16* yr = y + (u64)row * DM;
#pragma unroll
    for (int i = 0; i < 12; i++) {
        int c = lane + i * 64;
        yr[c] = (f16)((v[i] - mean) * rstd * g[c] + bta[c]);
    }
}

// ---------------- transpose fp32 -> f16 (dst[c*R+r] = src[r*C+c]) ----------------
__global__ __launch_bounds__(256) void transpose_kernel(const float* __restrict__ src,
                                                        f16* __restrict__ dst,
                                                        int R, int C) {
    __shared__ float tile[32][33];
    int bx = blockIdx.x * 32;
    int by = blockIdx.y * 32;
    int tx = threadIdx.x & 31, ty = threadIdx.x >> 5;
#pragma unroll
    for (int i = 0; i < 4; i++) {
        int r = by + ty + i * 8, c = bx + tx;
        if (r < R && c < C) tile[ty + i * 8][tx] = src[(u64)r * C + c];
    }
    __syncthreads();
#pragma unroll
    for (int i = 0; i < 4; i++) {
        int c = bx + ty + i * 8, r = by + tx;
        if (c < C && r < R) dst[(u64)c * R + r] = (f16)tile[tx][ty + i * 8];
    }
}

// ---------------- concat 3 bias vectors (768 each) ----------------
__global__ __launch_bounds__(256) void bias3_kernel(const float* __restrict__ a,
                                                    const float* __restrict__ b,
                                                    const float* __restrict__ c,
                                                    float* __restrict__ dst) {
    int i = blockIdx.x * 256 + threadIdx.x;
    if (i < 768) { dst[i] = a[i]; dst[i + 768] = b[i]; dst[i + 1536] = c[i]; }
}

// ---------------- GEMM v3: BK=64 + conflict-free swizzled LDS + XCD-stable grid ----------------
// C = A(BSxK,f16) @ Bt^T (Bt NxK f16) + bias [+gelu][+resid]
// LDS layout per matrix: 8 groups of 16 rows; group g, k-chunk c (8 f16), row r
// at byte offset g*2048 + c*256 + r*16. Staging inst q = wave*4+p writes the
// contiguous 1 KB at q*1024 (wave-uniform base + lane*16): lane -> row lane&15,
// chunk (q&1)*4 + (lane>>4). Fragment reads are 16-lane contiguous 16B blocks
// -> zero bank conflicts.
template <int NOUT, bool GELU, bool RESID, bool OUTF16>
__global__ __launch_bounds__(256) void gemm_kernel(const f16* __restrict__ A,
                                                   const f16* __restrict__ Bt,
                                                   const float* __restrict__ bias,
                                                   const float* __restrict__ resid,
                                                   float* __restrict__ Cf,
                                                   f16* __restrict__ Ch,
                                                   int K) {
    __shared__ __align__(16) f16 As[128 * 64];
    __shared__ __align__(16) f16 Bs[128 * 64];
    int id = blockIdx.x;
    int mb = id % MB_PAD, nb = id / MB_PAD;
    if (mb >= 99) return;
    int tid  = threadIdx.x;
    int lane = tid & 63, wave = tid >> 6;
    int wm = wave >> 1, wn = wave & 1;
    int m0 = mb * 128, n0 = nb * 128;
    int l15 = lane & 15, quad = lane >> 4;

    const f16* aptr[4]; const f16* bptr[4]; bool aok[4];
#pragma unroll
    for (int p = 0; p < 4; p++) {
        int q  = wave * 4 + p;
        int rl = (q >> 1) * 16 + l15;
        int ck = (q & 1) * 4 + quad;
        aptr[p] = A  + (u64)(m0 + rl) * K + ck * 8;
        aok[p]  = (m0 + rl) < BS;
        bptr[p] = Bt + (u64)(n0 + rl) * K + ck * 8;
    }

    f32x4 acc[4][4];
#pragma unroll
    for (int i = 0; i < 4; i++)
#pragma unroll
        for (int j = 0; j < 4; j++)
#pragma unroll
            for (int r = 0; r < 4; r++) acc[i][j][r] = 0.f;

    for (int k0 = 0; k0 < K; k0 += 64) {
#pragma unroll
        for (int p = 0; p < 4; p++) {
            int q = wave * 4 + p;
            if (aok[p])
                __builtin_amdgcn_global_load_lds((const AS1 void*)aptr[p],
                                                 (AS3 void*)((AS3 char*)As + q * 1024), 16, 0, 0);
            __builtin_amdgcn_global_load_lds((const AS1 void*)bptr[p],
                                             (AS3 void*)((AS3 char*)Bs + q * 1024), 16, 0, 0);
            aptr[p] += 64; bptr[p] += 64;
        }
        __syncthreads();
        f16x8 bf[4][2];
#pragma unroll
        for (int j = 0; j < 4; j++) {
            bf[j][0] = *(const f16x8*)((const char*)Bs + (wn * 4 + j) * 2048 + quad * 256 + l15 * 16);
            bf[j][1] = *(const f16x8*)((const char*)Bs + (wn * 4 + j) * 2048 + (4 + quad) * 256 + l15 * 16);
        }
#pragma unroll
        for (int i = 0; i < 4; i++) {
            f16x8 a0 = *(const f16x8*)((const char*)As + (wm * 4 + i) * 2048 + quad * 256 + l15 * 16);
            f16x8 a1 = *(const f16x8*)((const char*)As + (wm * 4 + i) * 2048 + (4 + quad) * 256 + l15 * 16);
#pragma unroll
            for (int j = 0; j < 4; j++) {
                acc[i][j] = __builtin_amdgcn_mfma_f32_16x16x32_f16(a0, bf[j][0], acc[i][j], 0, 0, 0);
                acc[i][j] = __builtin_amdgcn_mfma_f32_16x16x32_f16(a1, bf[j][1], acc[i][j], 0, 0, 0);
            }
        }
        __syncthreads();
    }

#pragma unroll
    for (int i = 0; i < 4; i++) {
#pragma unroll
        for (int j = 0; j < 4; j++) {
            int col = n0 + wn * 64 + j * 16 + l15;
            float bv = bias[col];
#pragma unroll
            for (int r = 0; r < 4; r++) {
                int row = m0 + wm * 64 + i * 16 + quad * 4 + r;
                if (row < BS) {
                    float v = acc[i][j][r] + bv;
                    if (GELU) v = 0.5f * v * (1.f + erff(v * 0.70710678118654752f));
                    if (RESID) v += resid[(u64)row * NOUT + col];
                    if (OUTF16) Ch[(u64)row * NOUT + col] = (f16)v;
                    else        Cf[(u64)row * NOUT + col] = v;
                }
            }
        }
    }
}

// ---------------- time attention: wave per (b,h,p); 8 queries x 9 keys ----------------
__global__ __launch_bounds__(256) void time_attn_kernel(const f16* __restrict__ qkv,
                                                        f16* __restrict__ ctx) {
    int w = blockIdx.x * 4 + (threadIdx.x >> 6);
    int lane = threadIdx.x & 63;
    int b = w / (NH * PP);
    int rem = w % (NH * PP);
    int h = rem / PP, p = rem % PP;
    u64 bb = (u64)b * SQ;
    int hoff = h * 64 + lane;

    float qv[TT], kv[9], vv[9];
#pragma unroll
    for (int t = 0; t < TT; t++) qv[t] = (float)qkv[(bb + 1 + t * PP + p) * QKVN + hoff];
    kv[0] = (float)qkv[bb * QKVN + 768 + hoff];
    vv[0] = (float)qkv[bb * QKVN + 1536 + hoff];
#pragma unroll
    for (int j = 1; j <= TT; j++) {
        u64 ro = (bb + 1 + (u64)(j - 1) * PP + p) * QKVN;
        kv[j] = (float)qkv[ro + 768 + hoff];
        vv[j] = (float)qkv[ro + 1536 + hoff];
    }
#pragma unroll
    for (int t = 0; t < TT; t++) {
        float s[9];
#pragma unroll
        for (int j = 0; j < 9; j++) {
            float ps = qv[t] * kv[j];
#pragma unroll
            for (int m = 1; m < 64; m <<= 1) ps += __shfl_xor(ps, m, 64);
            s[j] = ps * 0.125f;
        }
        float mx = s[0];
#pragma unroll
        for (int j = 1; j < 9; j++) mx = fmaxf(mx, s[j]);
        float sum = 0.f;
#pragma unroll
        for (int j = 0; j < 9; j++) { s[j] = expf(s[j] - mx); sum += s[j]; }
        float o = 0.f;
#pragma unroll
        for (int j = 0; j < 9; j++) o += s[j] * vv[j];
        o /= sum;
        ctx[(bb + 1 + (u64)t * PP + p) * DM + h * 64 + lane] = (f16)o;
    }
}

// ---------------- CLS attention split-K: part kernel, block per (b,h,chunk) ----------------
__global__ __launch_bounds__(256) void cls_part_kernel(const f16* __restrict__ qkv,
                                                       float* __restrict__ part) {
    int g = blockIdx.x;
    int c = g % CCH, bh = g / CCH;
    int b = bh / NH, h = bh % NH;
    u64 bb = (u64)b * SQ;
    int tid = threadIdx.x, lane = tid & 63, wave = tid >> 6;
    __shared__ float sc[CKEY];
    __shared__ float accbuf[4][64];
    __shared__ float lbuf[4];
    __shared__ float mxs;
    float qd = (float)qkv[bb * QKVN + h * 64 + lane];
    int j0 = c * CKEY;
    int cnt = SQ - j0; if (cnt > CKEY) cnt = CKEY;
    for (int jj = wave; jj < cnt; jj += 4) {
        float p = qd * (float)qkv[(bb + j0 + jj) * QKVN + 768 + h * 64 + lane];
#pragma unroll
        for (int m = 1; m < 64; m <<= 1) p += __shfl_xor(p, m, 64);
        if (lane == 0) sc[jj] = p * 0.125f;
    }
    __syncthreads();
    if (wave == 0) {
        float m = -1e30f;
        for (int j = lane; j < cnt; j += 64) m = fmaxf(m, sc[j]);
#pragma unroll
        for (int s = 1; s < 64; s <<= 1) m = fmaxf(m, __shfl_xor(m, s, 64));
        if (lane == 0) mxs = m;
    }
    __syncthreads();
    float mx = mxs;
    float acc = 0.f, l = 0.f;
    for (int jj = wave; jj < cnt; jj += 4) {
        float w = expf(sc[jj] - mx);
        l += w;
        acc += w * (float)qkv[(bb + j0 + jj) * QKVN + 1536 + h * 64 + lane];
    }
    accbuf[wave][lane] = acc;
    if (lane == 0) lbuf[wave] = l;
    __syncthreads();
    if (tid < 64) {
        float a = accbuf[0][tid] + accbuf[1][tid] + accbuf[2][tid] + accbuf[3][tid];
        float* pb = part + ((u64)bh * CCH + c) * 66;
        if (tid == 0) { pb[0] = mxs; pb[1] = lbuf[0] + lbuf[1] + lbuf[2] + lbuf[3]; }
        pb[2 + tid] = a;
    }
}

// ---------------- CLS attention split-K: combine kernel, wave per (b,h) ----------------
__global__ __launch_bounds__(256) void cls_comb_kernel(const float* __restrict__ part,
                                                       f16* __restrict__ ctx) {
    int w = blockIdx.x * 4 + (threadIdx.x >> 6);
    int lane = threadIdx.x & 63;
    if (w >= BQ * NH) return;
    int b = w / NH, h = w % NH;
    const float* pb = part + (u64)w * CCH * 66;
    float m = (lane < CCH) ? pb[lane * 66] : -1e30f;
#pragma unroll
    for (int s = 1; s < 64; s <<= 1) m = fmaxf(m, __shfl_xor(m, s, 64));
    float l = (lane < CCH) ? pb[lane * 66 + 1] * expf(pb[lane * 66] - m) : 0.f;
#pragma unroll
    for (int s = 1; s < 64; s <<= 1) l += __shfl_xor(l, s, 64);
    float o = 0.f;
    for (int j = 0; j < CCH; j++) {
        float mj = pb[j * 66];
        o += pb[j * 66 + 2 + lane] * expf(mj - m);
    }
    ctx[((u64)b * SQ) * DM + h * 64 + lane] = (f16)(o / l);
}

// ---------------- space attention: MFMA flash, block per (b,h,t) ----------------
__global__ __launch_bounds__(256) void space_attn_kernel(const f16* __restrict__ qkv,
                                                         f16* __restrict__ ctx) {
    int g = blockIdx.x;
    int b = g / (NH * TT);
    int rem = g % (NH * TT);
    int h = rem / TT, t = rem % TT;
    __shared__ __align__(16) f16 Vt[64 * 232];
    __shared__ __align__(16) f16 Ps[4 * 16 * 232];
    u64 bb = (u64)b * SQ;
    int tid = threadIdx.x, lane = tid & 63, wave = tid >> 6;
    int l15 = lane & 15, quad = lane >> 4;

    for (int i = tid; i < 4 * 16 * 232 * 2 / 16; i += 256)
        ((uint4*)Ps)[i] = make_uint4(0u, 0u, 0u, 0u);

    for (int idx = tid; idx < 232 * 8; idx += 256) {
        int c8 = idx / 232;
        int j  = idx - c8 * 232;
        int c  = c8 * 8;
        uint4 vraw = make_uint4(0u, 0u, 0u, 0u);
        if (j < 197) {
            int tok = (j == 0) ? 0 : (1 + t * PP + (j - 1));
            vraw = *(const uint4*)(qkv + (bb + tok) * QKVN + 1536 + h * 64 + c);
        }
        f16x8 vv = *(f16x8*)&vraw;
#pragma unroll
        for (int e = 0; e < 8; e++) Vt[(c + e) * 232 + j] = vv[e];
    }
    __syncthreads();

    f16* myP = Ps + wave * 16 * 232;
    for (int qt = wave; qt < 13; qt += 4) {
        int mloc = qt * 16 + l15;
        int mc = mloc > 195 ? 195 : mloc;
        const f16* qr = qkv + (bb + 1 + (u64)t * PP + mc) * QKVN + h * 64;
        f16x8 qa0 = *(const f16x8*)(qr + quad * 8);
        f16x8 qa1 = *(const f16x8*)(qr + 32 + quad * 8);

        f32x4 s[13];
#pragma unroll
        for (int nt = 0; nt < 13; nt++) { s[nt][0] = 0.f; s[nt][1] = 0.f; s[nt][2] = 0.f; s[nt][3] = 0.f; }
#pragma unroll
        for (int nt = 0; nt < 13; nt++) {
            int n = nt * 16 + l15;
            int ncl = n > 196 ? 196 : n;
            int tok = (ncl == 0) ? 0 : (1 + t * PP + (ncl - 1));
            const f16* kr = qkv + (bb + tok) * QKVN + 768 + h * 64;
            f16x8 kb0 = *(const f16x8*)(kr + quad * 8);
            f16x8 kb1 = *(const f16x8*)(kr + 32 + quad * 8);
            s[nt] = __builtin_amdgcn_mfma_f32_16x16x32_f16(qa0, kb0, s[nt], 0, 0, 0);
            s[nt] = __builtin_amdgcn_mfma_f32_16x16x32_f16(qa1, kb1, s[nt], 0, 0, 0);
        }
        if (l15 >= 5) { s[12][0] = -1e30f; s[12][1] = -1e30f; s[12][2] = -1e30f; s[12][3] = -1e30f; }

        float mx[4] = {-1e30f, -1e30f, -1e30f, -1e30f};
#pragma unroll
        for (int nt = 0; nt < 13; nt++)
#pragma unroll
            for (int r = 0; r < 4; r++) mx[r] = fmaxf(mx[r], s[nt][r]);
#pragma unroll
        for (int m = 1; m < 16; m <<= 1)
#pragma unroll
            for (int r = 0; r < 4; r++) mx[r] = fmaxf(mx[r], __shfl_xor(mx[r], m, 64));

        float sum[4] = {0.f, 0.f, 0.f, 0.f};
#pragma unroll
        for (int nt = 0; nt < 13; nt++)
#pragma unroll
            for (int r = 0; r < 4; r++) {
                float p = exp2f((s[nt][r] - mx[r]) * 0.18033688011112042f);
                s[nt][r] = p;
                sum[r] += p;
            }
#pragma unroll
        for (int m = 1; m < 16; m <<= 1)
#pragma unroll
            for (int r = 0; r < 4; r++) sum[r] += __shfl_xor(sum[r], m, 64);

#pragma unroll
        for (int nt = 0; nt < 13; nt++)
#pragma unroll
            for (int r = 0; r < 4; r++)
                myP[(quad * 4 + r) * 232 + nt * 16 + l15] = (f16)s[nt][r];

        f32x4 o[4];
#pragma unroll
        for (int n2 = 0; n2 < 4; n2++) { o[n2][0] = 0.f; o[n2][1] = 0.f; o[n2][2] = 0.f; o[n2][3] = 0.f; }
#pragma unroll
        for (int kc = 0; kc < 7; kc++) {
            f16x8 pa = *(const f16x8*)(&myP[l15 * 232 + kc * 32 + quad * 8]);
#pragma unroll
            for (int n2 = 0; n2 < 4; n2++) {
                f16x8 vb = *(const f16x8*)(&Vt[(n2 * 16 + l15) * 232 + kc * 32 + quad * 8]);
                o[n2] = __builtin_amdgcn_mfma_f32_16x16x32_f16(pa, vb, o[n2], 0, 0, 0);
            }
        }

        float inv[4];
#pragma unroll
        for (int r = 0; r < 4; r++) inv[r] = 1.f / sum[r];
#pragma unroll
        for (int n2 = 0; n2 < 4; n2++)
#pragma unroll
            for (int r = 0; r < 4; r++) {
                int m = qt * 16 + quad * 4 + r;
                if (m < PP)
                    ctx[(bb + 1 + (u64)t * PP + m) * DM + h * 64 + n2 * 16 + l15] = (f16)(o[n2][r] * inv[r]);
            }
    }
}

// ---------------- host ----------------
extern "C" void kernel_launch(void* const* d_in, const int* in_sizes, int n_in,
                              void* d_out, int out_size, void* d_ws, size_t ws_size,
                              hipStream_t stream) {
    const float* x_in  = (const float*)d_in[0];
    const float* t_Wq  = (const float*)d_in[1];
    const float* t_bq  = (const float*)d_in[2];
    const float* t_Wk  = (const float*)d_in[3];
    const float* t_bk  = (const float*)d_in[4];
    const float* t_Wv  = (const float*)d_in[5];
    const float* t_bv  = (const float*)d_in[6];
    const float* t_Wo  = (const float*)d_in[7];
    const float* t_bo  = (const float*)d_in[8];
    const float* s_Wq  = (const float*)d_in[9];
    const float* s_bq  = (const float*)d_in[10];
    const float* s_Wk  = (const float*)d_in[11];
    const float* s_bk  = (const float*)d_in[12];
    const float* s_Wv  = (const float*)d_in[13];
    const float* s_bv  = (const float*)d_in[14];
    const float* s_Wo  = (const float*)d_in[15];
    const float* s_bo  = (const float*)d_in[16];
    const float* W1    = (const float*)d_in[17];
    const float* b1    = (const float*)d_in[18];
    const float* W2    = (const float*)d_in[19];
    const float* b2    = (const float*)d_in[20];
    const float* ln1g  = (const float*)d_in[21];
    const float* ln1b  = (const float*)d_in[22];
    const float* ln2g  = (const float*)d_in[23];
    const float* ln2b  = (const float*)d_in[24];
    const float* ln3g  = (const float*)d_in[25];
    const float* ln3b  = (const float*)d_in[26];

    char* ws = (char*)d_ws;
    f16* y    = (f16*)(ws + Y_OFF);
    f16* qkv  = (f16*)(ws + QKV_OFF);
    f16* ctx  = (f16*)(ws + CTX_OFF);
    f16* hbuf = (f16*)(ws + H_OFF);
    float* clsP = (float*)(ws + Y_OFF);   // reuses dead y region
    char* wreg = ws + W_OFF;
    f16* tQKV  = (f16*)(wreg);
    f16* tWoT  = (f16*)(wreg + 3538944);
    f16* sQKV  = (f16*)(wreg + 4718592);
    f16* sWoT  = (f16*)(wreg + 8257536);
    f16* W1T   = (f16*)(wreg + 9437184);
    f16* W2T   = (f16*)(wreg + 14155776);
    float* tBias = (float*)(wreg + 18874368);
    float* sBias = (float*)(wreg + 18883584);
    float* xcur  = (float*)d_out;

    dim3 tb(256);
    // --- weight prep ---
    transpose_kernel<<<dim3(24, 24), tb, 0, stream>>>(t_Wq, tQKV, 768, 768);
    transpose_kernel<<<dim3(24, 24), tb, 0, stream>>>(t_Wk, tQKV + 768 * 768, 768, 768);
    transpose_kernel<<<dim3(24, 24), tb, 0, stream>>>(t_Wv, tQKV + 2 * 768 * 768, 768, 768);
    transpose_kernel<<<dim3(24, 24), tb, 0, stream>>>(t_Wo, tWoT, 768, 768);
    transpose_kernel<<<dim3(24, 24), tb, 0, stream>>>(s_Wq, sQKV, 768, 768);
    transpose_kernel<<<dim3(24, 24), tb, 0, stream>>>(s_Wk, sQKV + 768 * 768, 768, 768);
    transpose_kernel<<<dim3(24, 24), tb, 0, stream>>>(s_Wv, sQKV + 2 * 768 * 768, 768, 768);
    transpose_kernel<<<dim3(24, 24), tb, 0, stream>>>(s_Wo, sWoT, 768, 768);
    transpose_kernel<<<dim3(96, 24), tb, 0, stream>>>(W1, W1T, 768, 3072);
    transpose_kernel<<<dim3(24, 96), tb, 0, stream>>>(W2, W2T, 3072, 768);
    bias3_kernel<<<3, tb, 0, stream>>>(t_bq, t_bk, t_bv, tBias);
    bias3_kernel<<<3, tb, 0, stream>>>(s_bq, s_bk, s_bv, sBias);

    // --- phase A: time MHA ---
    ln_kernel<<<3138, tb, 0, stream>>>(x_in, ln1g, ln1b, y);
    gemm_kernel<QKVN, false, false, true><<<MB_PAD * 18, tb, 0, stream>>>(y, tQKV, tBias, nullptr, nullptr, qkv, 768);
    time_attn_kernel<<<4704, tb, 0, stream>>>(qkv, ctx);
    cls_part_kernel<<<BQ * NH * CCH, tb, 0, stream>>>(qkv, clsP);
    cls_comb_kernel<<<24, tb, 0, stream>>>(clsP, ctx);
    gemm_kernel<DM, false, true, false><<<MB_PAD * 6, tb, 0, stream>>>(ctx, tWoT, t_bo, x_in, xcur, nullptr, 768);

    // --- phase B: space MHA ---
    ln_kernel<<<3138, tb, 0, stream>>>(xcur, ln2g, ln2b, y);
    gemm_kernel<QKVN, false, false, true><<<MB_PAD * 18, tb, 0, stream>>>(y, sQKV, sBias, nullptr, nullptr, qkv, 768);
    space_attn_kernel<<<768, tb, 0, stream>>>(qkv, ctx);
    cls_part_kernel<<<BQ * NH * CCH, tb, 0, stream>>>(qkv, clsP);
    cls_comb_kernel<<<24, tb, 0, stream>>>(clsP, ctx);
    gemm_kernel<DM, false, true, false><<<MB_PAD * 6, tb, 0, stream>>>(ctx, sWoT, s_bo, xcur, xcur, nullptr, 768);

    // --- phase C: MLP ---
    ln_kernel<<<3138, tb, 0, stream>>>(xcur, ln3g, ln3b, y);
    gemm_kernel<D4, true, false, true><<<MB_PAD * 24, tb, 0, stream>>>(y, W1T, b1, nullptr, nullptr, hbuf, 768);
    gemm_kernel<DM, false, true, false><<<MB_PAD * 6, tb, 0, stream>>>(hbuf, W2T, b2, xcur, xcur, nullptr, 3072);
}

// Round 6
// 901.613 us; speedup vs baseline: 1.2091x; 1.2091x over previous
//
#include <hip/hip_runtime.h>

// ---------------- problem constants ----------------
#define BQ   8
#define SQ   1569
#define BS   12552      // BQ*SQ
#define DM   768
#define NH   12
#define DH   64
#define TT   8
#define PP   196
#define D4   3072
#define QKVN 2304
#define CCH  24         // CLS split-K chunks
#define CKEY 66         // keys per chunk (24*66 = 1584 >= 1569)
#define MB_PAD 104      // 99 m-blocks padded to multiple of 8 for XCD-stable swizzle

typedef _Float16 f16;
typedef _Float16 f16x8 __attribute__((ext_vector_type(8)));
typedef float    f32x4 __attribute__((ext_vector_type(4)));
typedef unsigned long long u64;

#define AS1 __attribute__((address_space(1)))
#define AS3 __attribute__((address_space(3)))

#define Y_OFF    0ULL
#define QKV_OFF  19279872ULL
#define CTX_OFF  77119488ULL
#define H_OFF    19279872ULL
#define W_OFF    96399360ULL

// ---------------- LayerNorm (wave per row) ----------------
__global__ __launch_bounds__(256) void ln_kernel(const float* __restrict__ x,
                                                 const float* __restrict__ g,
                                                 const float* __restrict__ bta,
                                                 f16* __restrict__ y) {
    int row = blockIdx.x * 4 + (threadIdx.x >> 6);
    int lane = threadIdx.x & 63;
    if (row >= BS) return;
    const float* xr = x + (u64)row * DM;
    float v[12];
    float s = 0.f, s2 = 0.f;
#pragma unroll
    for (int i = 0; i < 12; i++) { v[i] = xr[lane + i * 64]; s += v[i]; s2 += v[i] * v[i]; }
#pragma unroll
    for (int m = 1; m < 64; m <<= 1) { s += __shfl_xor(s, m, 64); s2 += __shfl_xor(s2, m, 64); }
    float mean = s * (1.f / 768.f);
    float var  = s2 * (1.f / 768.f) - mean * mean;
    float rstd = rsqrtf(var + 1e-12f);
    f16* yr = y + (u64)row * DM;
#pragma unroll
    for (int i = 0; i < 12; i++) {
        int c = lane + i * 64;
        yr[c] = (f16)((v[i] - mean) * rstd * g[c] + bta[c]);
    }
}

// ---------------- transpose fp32 -> f16 (dst[c*R+r] = src[r*C+c]) ----------------
__global__ __launch_bounds__(256) void transpose_kernel(const float* __restrict__ src,
                                                        f16* __restrict__ dst,
                                                        int R, int C) {
    __shared__ float tile[32][33];
    int bx = blockIdx.x * 32;
    int by = blockIdx.y * 32;
    int tx = threadIdx.x & 31, ty = threadIdx.x >> 5;
#pragma unroll
    for (int i = 0; i < 4; i++) {
        int r = by + ty + i * 8, c = bx + tx;
        if (r < R && c < C) tile[ty + i * 8][tx] = src[(u64)r * C + c];
    }
    __syncthreads();
#pragma unroll
    for (int i = 0; i < 4; i++) {
        int c = bx + ty + i * 8, r = by + tx;
        if (c < C && r < R) dst[(u64)c * R + r] = (f16)tile[tx][ty + i * 8];
    }
}

// ---------------- concat 3 bias vectors (768 each) ----------------
__global__ __launch_bounds__(256) void bias3_kernel(const float* __restrict__ a,
                                                    const float* __restrict__ b,
                                                    const float* __restrict__ c,
                                                    float* __restrict__ dst) {
    int i = blockIdx.x * 256 + threadIdx.x;
    if (i < 768) { dst[i] = a[i]; dst[i + 768] = b[i]; dst[i + 1536] = c[i]; }
}

// ---------------- GEMM v4: R4 pattern + xor-swizzled LDS + 1-barrier double buffer ----
// C = A(BSxK,f16) @ Bt^T (Bt NxK f16) + bias [+gelu][+resid]
// Grid: id = nb*MB_PAD + mb (mb fastest -> id%8 == mb%8, XCD-stable A slices).
// Staging (R4 global pattern, unchanged coalescing): wave w, lane -> row
// w*16+(lane>>2) (+64), 64B cluster per 4 lanes; within-row chunk xor-swizzled
// by (row&3) so fragment reads land on distinct bank groups.
// K-loop: double-buffered, ONE barrier per iter; loads for k+1 issued right
// after the barrier, in flight during ds_read+MFMA of k.
template <int NOUT, bool GELU, bool RESID, bool OUTF16>
__global__ __launch_bounds__(256) void gemm_kernel(const f16* __restrict__ A,
                                                   const f16* __restrict__ Bt,
                                                   const float* __restrict__ bias,
                                                   const float* __restrict__ resid,
                                                   float* __restrict__ Cf,
                                                   f16* __restrict__ Ch,
                                                   int K) {
    __shared__ __align__(16) f16 As[2][128 * 32];
    __shared__ __align__(16) f16 Bs[2][128 * 32];
    int id = blockIdx.x;
    int mb = id % MB_PAD, nb = id / MB_PAD;
    if (mb >= 99) return;
    int tid  = threadIdx.x;
    int lane = tid & 63, wave = tid >> 6;
    int wm = wave >> 1, wn = wave & 1;
    int m0 = mb * 128, n0 = nb * 128;
    int l15 = lane & 15, quad = lane >> 4;

    // staging addressing (R4) + xor swizzle on within-row chunk
    int r0   = wave * 16 + (lane >> 2);
    int coff = (((lane & 3) ^ (r0 & 3))) * 8;   // cluster still covers same 64B of the row
    const f16* ag0 = A + (u64)(m0 + r0) * K + coff;
    const f16* ag1 = A + (u64)(m0 + r0 + 64) * K + coff;   // (r0+64)&3 == r0&3
    bool av0 = (m0 + r0) < BS, av1 = (m0 + r0 + 64) < BS;
    const f16* bg0 = Bt + (u64)(n0 + r0) * K + coff;
    const f16* bg1 = Bt + (u64)(n0 + r0 + 64) * K + coff;
    int lofs = wave * 1024;

    f32x4 acc[4][4];
#pragma unroll
    for (int i = 0; i < 4; i++)
#pragma unroll
        for (int j = 0; j < 4; j++)
#pragma unroll
            for (int r = 0; r < 4; r++) acc[i][j][r] = 0.f;

    // prologue: stage tile 0 into buffer 0
    if (av0) __builtin_amdgcn_global_load_lds((const AS1 void*)ag0, (AS3 void*)((AS3 char*)&As[0][0] + lofs), 16, 0, 0);
    if (av1) __builtin_amdgcn_global_load_lds((const AS1 void*)ag1, (AS3 void*)((AS3 char*)&As[0][0] + lofs + 4096), 16, 0, 0);
    __builtin_amdgcn_global_load_lds((const AS1 void*)bg0, (AS3 void*)((AS3 char*)&Bs[0][0] + lofs), 16, 0, 0);
    __builtin_amdgcn_global_load_lds((const AS1 void*)bg1, (AS3 void*)((AS3 char*)&Bs[0][0] + lofs + 4096), 16, 0, 0);
    ag0 += 32; ag1 += 32; bg0 += 32; bg1 += 32;

    int nit = K >> 5;
    for (int it = 0; it < nit; it++) {
        __syncthreads();                 // drains staging for buffer it&1 (vmcnt 0)
        int buf = it & 1;
        if (it + 1 < nit) {              // prefetch next tile into other buffer
            int nb2 = buf ^ 1;
            if (av0) __builtin_amdgcn_global_load_lds((const AS1 void*)ag0, (AS3 void*)((AS3 char*)&As[nb2][0] + lofs), 16, 0, 0);
            if (av1) __builtin_amdgcn_global_load_lds((const AS1 void*)ag1, (AS3 void*)((AS3 char*)&As[nb2][0] + lofs + 4096), 16, 0, 0);
            __builtin_amdgcn_global_load_lds((const AS1 void*)bg0, (AS3 void*)((AS3 char*)&Bs[nb2][0] + lofs), 16, 0, 0);
            __builtin_amdgcn_global_load_lds((const AS1 void*)bg1, (AS3 void*)((AS3 char*)&Bs[nb2][0] + lofs + 4096), 16, 0, 0);
            ag0 += 32; ag1 += 32; bg0 += 32; bg1 += 32;
        }
        f16x8 af[4], bf[4];
#pragma unroll
        for (int i = 0; i < 4; i++) {
            int row = wm * 64 + i * 16 + l15;
            af[i] = *(const f16x8*)(&As[buf][row * 32 + ((quad ^ (l15 & 3)) * 8)]);
        }
#pragma unroll
        for (int j = 0; j < 4; j++) {
            int row = wn * 64 + j * 16 + l15;
            bf[j] = *(const f16x8*)(&Bs[buf][row * 32 + ((quad ^ (l15 & 3)) * 8)]);
        }
#pragma unroll
        for (int i = 0; i < 4; i++)
#pragma unroll
            for (int j = 0; j < 4; j++)
                acc[i][j] = __builtin_amdgcn_mfma_f32_16x16x32_f16(af[i], bf[j], acc[i][j], 0, 0, 0);
    }

#pragma unroll
    for (int i = 0; i < 4; i++) {
#pragma unroll
        for (int j = 0; j < 4; j++) {
            int col = n0 + wn * 64 + j * 16 + l15;
            float bv = bias[col];
#pragma unroll
            for (int r = 0; r < 4; r++) {
                int row = m0 + wm * 64 + i * 16 + quad * 4 + r;
                if (row < BS) {
                    float v = acc[i][j][r] + bv;
                    if (GELU) v = 0.5f * v * (1.f + erff(v * 0.70710678118654752f));
                    if (RESID) v += resid[(u64)row * NOUT + col];
                    if (OUTF16) Ch[(u64)row * NOUT + col] = (f16)v;
                    else        Cf[(u64)row * NOUT + col] = v;
                }
            }
        }
    }
}

// ---------------- time attention: wave per (b,h,p); 8 queries x 9 keys ----------------
__global__ __launch_bounds__(256) void time_attn_kernel(const f16* __restrict__ qkv,
                                                        f16* __restrict__ ctx) {
    int w = blockIdx.x * 4 + (threadIdx.x >> 6);
    int lane = threadIdx.x & 63;
    int b = w / (NH * PP);
    int rem = w % (NH * PP);
    int h = rem / PP, p = rem % PP;
    u64 bb = (u64)b * SQ;
    int hoff = h * 64 + lane;

    float qv[TT], kv[9], vv[9];
#pragma unroll
    for (int t = 0; t < TT; t++) qv[t] = (float)qkv[(bb + 1 + t * PP + p) * QKVN + hoff];
    kv[0] = (float)qkv[bb * QKVN + 768 + hoff];
    vv[0] = (float)qkv[bb * QKVN + 1536 + hoff];
#pragma unroll
    for (int j = 1; j <= TT; j++) {
        u64 ro = (bb + 1 + (u64)(j - 1) * PP + p) * QKVN;
        kv[j] = (float)qkv[ro + 768 + hoff];
        vv[j] = (float)qkv[ro + 1536 + hoff];
    }
#pragma unroll
    for (int t = 0; t < TT; t++) {
        float s[9];
#pragma unroll
        for (int j = 0; j < 9; j++) {
            float ps = qv[t] * kv[j];
#pragma unroll
            for (int m = 1; m < 64; m <<= 1) ps += __shfl_xor(ps, m, 64);
            s[j] = ps * 0.125f;
        }
        float mx = s[0];
#pragma unroll
        for (int j = 1; j < 9; j++) mx = fmaxf(mx, s[j]);
        float sum = 0.f;
#pragma unroll
        for (int j = 0; j < 9; j++) { s[j] = expf(s[j] - mx); sum += s[j]; }
        float o = 0.f;
#pragma unroll
        for (int j = 0; j < 9; j++) o += s[j] * vv[j];
        o /= sum;
        ctx[(bb + 1 + (u64)t * PP + p) * DM + h * 64 + lane] = (f16)o;
    }
}

// ---------------- CLS attention split-K: part kernel, block per (b,h,chunk) ----------------
__global__ __launch_bounds__(256) void cls_part_kernel(const f16* __restrict__ qkv,
                                                       float* __restrict__ part) {
    int g = blockIdx.x;
    int c = g % CCH, bh = g / CCH;
    int b = bh / NH, h = bh % NH;
    u64 bb = (u64)b * SQ;
    int tid = threadIdx.x, lane = tid & 63, wave = tid >> 6;
    __shared__ float sc[CKEY];
    __shared__ float accbuf[4][64];
    __shared__ float lbuf[4];
    __shared__ float mxs;
    float qd = (float)qkv[bb * QKVN + h * 64 + lane];
    int j0 = c * CKEY;
    int cnt = SQ - j0; if (cnt > CKEY) cnt = CKEY;
    for (int jj = wave; jj < cnt; jj += 4) {
        float p = qd * (float)qkv[(bb + j0 + jj) * QKVN + 768 + h * 64 + lane];
#pragma unroll
        for (int m = 1; m < 64; m <<= 1) p += __shfl_xor(p, m, 64);
        if (lane == 0) sc[jj] = p * 0.125f;
    }
    __syncthreads();
    if (wave == 0) {
        float m = -1e30f;
        for (int j = lane; j < cnt; j += 64) m = fmaxf(m, sc[j]);
#pragma unroll
        for (int s = 1; s < 64; s <<= 1) m = fmaxf(m, __shfl_xor(m, s, 64));
        if (lane == 0) mxs = m;
    }
    __syncthreads();
    float mx = mxs;
    float acc = 0.f, l = 0.f;
    for (int jj = wave; jj < cnt; jj += 4) {
        float w = expf(sc[jj] - mx);
        l += w;
        acc += w * (float)qkv[(bb + j0 + jj) * QKVN + 1536 + h * 64 + lane];
    }
    accbuf[wave][lane] = acc;
    if (lane == 0) lbuf[wave] = l;
    __syncthreads();
    if (tid < 64) {
        float a = accbuf[0][tid] + accbuf[1][tid] + accbuf[2][tid] + accbuf[3][tid];
        float* pb = part + ((u64)bh * CCH + c) * 66;
        if (tid == 0) { pb[0] = mxs; pb[1] = lbuf[0] + lbuf[1] + lbuf[2] + lbuf[3]; }
        pb[2 + tid] = a;
    }
}

// ---------------- CLS attention split-K: combine kernel, wave per (b,h) ----------------
__global__ __launch_bounds__(256) void cls_comb_kernel(const float* __restrict__ part,
                                                       f16* __restrict__ ctx) {
    int w = blockIdx.x * 4 + (threadIdx.x >> 6);
    int lane = threadIdx.x & 63;
    if (w >= BQ * NH) return;
    int b = w / NH, h = w % NH;
    const float* pb = part + (u64)w * CCH * 66;
    float m = (lane < CCH) ? pb[lane * 66] : -1e30f;
#pragma unroll
    for (int s = 1; s < 64; s <<= 1) m = fmaxf(m, __shfl_xor(m, s, 64));
    float l = (lane < CCH) ? pb[lane * 66 + 1] * expf(pb[lane * 66] - m) : 0.f;
#pragma unroll
    for (int s = 1; s < 64; s <<= 1) l += __shfl_xor(l, s, 64);
    float o = 0.f;
    for (int j = 0; j < CCH; j++) {
        float mj = pb[j * 66];
        o += pb[j * 66 + 2 + lane] * expf(mj - m);
    }
    ctx[((u64)b * SQ) * DM + h * 64 + lane] = (f16)(o / l);
}

// ---------------- space attention: MFMA flash, block per (b,h,t) ----------------
__global__ __launch_bounds__(256) void space_attn_kernel(const f16* __restrict__ qkv,
                                                         f16* __restrict__ ctx) {
    int g = blockIdx.x;
    int b = g / (NH * TT);
    int rem = g % (NH * TT);
    int h = rem / TT, t = rem % TT;
    __shared__ __align__(16) f16 Vt[64 * 232];
    __shared__ __align__(16) f16 Ps[4 * 16 * 232];
    u64 bb = (u64)b * SQ;
    int tid = threadIdx.x, lane = tid & 63, wave = tid >> 6;
    int l15 = lane & 15, quad = lane >> 4;

    for (int i = tid; i < 4 * 16 * 232 * 2 / 16; i += 256)
        ((uint4*)Ps)[i] = make_uint4(0u, 0u, 0u, 0u);

    for (int idx = tid; idx < 232 * 8; idx += 256) {
        int c8 = idx / 232;
        int j  = idx - c8 * 232;
        int c  = c8 * 8;
        uint4 vraw = make_uint4(0u, 0u, 0u, 0u);
        if (j < 197) {
            int tok = (j == 0) ? 0 : (1 + t * PP + (j - 1));
            vraw = *(const uint4*)(qkv + (bb + tok) * QKVN + 1536 + h * 64 + c);
        }
        f16x8 vv = *(f16x8*)&vraw;
#pragma unroll
        for (int e = 0; e < 8; e++) Vt[(c + e) * 232 + j] = vv[e];
    }
    __syncthreads();

    f16* myP = Ps + wave * 16 * 232;
    for (int qt = wave; qt < 13; qt += 4) {
        int mloc = qt * 16 + l15;
        int mc = mloc > 195 ? 195 : mloc;
        const f16* qr = qkv + (bb + 1 + (u64)t * PP + mc) * QKVN + h * 64;
        f16x8 qa0 = *(const f16x8*)(qr + quad * 8);
        f16x8 qa1 = *(const f16x8*)(qr + 32 + quad * 8);

        f32x4 s[13];
#pragma unroll
        for (int nt = 0; nt < 13; nt++) { s[nt][0] = 0.f; s[nt][1] = 0.f; s[nt][2] = 0.f; s[nt][3] = 0.f; }
#pragma unroll
        for (int nt = 0; nt < 13; nt++) {
            int n = nt * 16 + l15;
            int ncl = n > 196 ? 196 : n;
            int tok = (ncl == 0) ? 0 : (1 + t * PP + (ncl - 1));
            const f16* kr = qkv + (bb + tok) * QKVN + 768 + h * 64;
            f16x8 kb0 = *(const f16x8*)(kr + quad * 8);
            f16x8 kb1 = *(const f16x8*)(kr + 32 + quad * 8);
            s[nt] = __builtin_amdgcn_mfma_f32_16x16x32_f16(qa0, kb0, s[nt], 0, 0, 0);
            s[nt] = __builtin_amdgcn_mfma_f32_16x16x32_f16(qa1, kb1, s[nt], 0, 0, 0);
        }
        if (l15 >= 5) { s[12][0] = -1e30f; s[12][1] = -1e30f; s[12][2] = -1e30f; s[12][3] = -1e30f; }

        float mx[4] = {-1e30f, -1e30f, -1e30f, -1e30f};
#pragma unroll
        for (int nt = 0; nt < 13; nt++)
#pragma unroll
            for (int r = 0; r < 4; r++) mx[r] = fmaxf(mx[r], s[nt][r]);
#pragma unroll
        for (int m = 1; m < 16; m <<= 1)
#pragma unroll
            for (int r = 0; r < 4; r++) mx[r] = fmaxf(mx[r], __shfl_xor(mx[r], m, 64));

        float sum[4] = {0.f, 0.f, 0.f, 0.f};
#pragma unroll
        for (int nt = 0; nt < 13; nt++)
#pragma unroll
            for (int r = 0; r < 4; r++) {
                float p = exp2f((s[nt][r] - mx[r]) * 0.18033688011112042f);
                s[nt][r] = p;
                sum[r] += p;
            }
#pragma unroll
        for (int m = 1; m < 16; m <<= 1)
#pragma unroll
            for (int r = 0; r < 4; r++) sum[r] += __shfl_xor(sum[r], m, 64);

#pragma unroll
        for (int nt = 0; nt < 13; nt++)
#pragma unroll
            for (int r = 0; r < 4; r++)
                myP[(quad * 4 + r) * 232 + nt * 16 + l15] = (f16)s[nt][r];

        f32x4 o[4];
#pragma unroll
        for (int n2 = 0; n2 < 4; n2++) { o[n2][0] = 0.f; o[n2][1] = 0.f; o[n2][2] = 0.f; o[n2][3] = 0.f; }
#pragma unroll
        for (int kc = 0; kc < 7; kc++) {
            f16x8 pa = *(const f16x8*)(&myP[l15 * 232 + kc * 32 + quad * 8]);
#pragma unroll
            for (int n2 = 0; n2 < 4; n2++) {
                f16x8 vb = *(const f16x8*)(&Vt[(n2 * 16 + l15) * 232 + kc * 32 + quad * 8]);
                o[n2] = __builtin_amdgcn_mfma_f32_16x16x32_f16(pa, vb, o[n2], 0, 0, 0);
            }
        }

        float inv[4];
#pragma unroll
        for (int r = 0; r < 4; r++) inv[r] = 1.f / sum[r];
#pragma unroll
        for (int n2 = 0; n2 < 4; n2++)
#pragma unroll
            for (int r = 0; r < 4; r++) {
                int m = qt * 16 + quad * 4 + r;
                if (m < PP)
                    ctx[(bb + 1 + (u64)t * PP + m) * DM + h * 64 + n2 * 16 + l15] = (f16)(o[n2][r] * inv[r]);
            }
    }
}

// ---------------- host ----------------
extern "C" void kernel_launch(void* const* d_in, const int* in_sizes, int n_in,
                              void* d_out, int out_size, void* d_ws, size_t ws_size,
                              hipStream_t stream) {
    const float* x_in  = (const float*)d_in[0];
    const float* t_Wq  = (const float*)d_in[1];
    const float* t_bq  = (const float*)d_in[2];
    const float* t_Wk  = (const float*)d_in[3];
    const float* t_bk  = (const float*)d_in[4];
    const float* t_Wv  = (const float*)d_in[5];
    const float* t_bv  = (const float*)d_in[6];
    const float* t_Wo  = (const float*)d_in[7];
    const float* t_bo  = (const float*)d_in[8];
    const float* s_Wq  = (const float*)d_in[9];
    const float* s_bq  = (const float*)d_in[10];
    const float* s_Wk  = (const float*)d_in[11];
    const float* s_bk  = (const float*)d_in[12];
    const float* s_Wv  = (const float*)d_in[13];
    const float* s_bv  = (const float*)d_in[14];
    const float* s_Wo  = (const float*)d_in[15];
    const float* s_bo  = (const float*)d_in[16];
    const float* W1    = (const float*)d_in[17];
    const float* b1    = (const float*)d_in[18];
    const float* W2    = (const float*)d_in[19];
    const float* b2    = (const float*)d_in[20];
    const float* ln1g  = (const float*)d_in[21];
    const float* ln1b  = (const float*)d_in[22];
    const float* ln2g  = (const float*)d_in[23];
    const float* ln2b  = (const float*)d_in[24];
    const float* ln3g  = (const float*)d_in[25];
    const float* ln3b  = (const float*)d_in[26];

    char* ws = (char*)d_ws;
    f16* y    = (f16*)(ws + Y_OFF);
    f16* qkv  = (f16*)(ws + QKV_OFF);
    f16* ctx  = (f16*)(ws + CTX_OFF);
    f16* hbuf = (f16*)(ws + H_OFF);
    float* clsP = (float*)(ws + Y_OFF);   // reuses dead y region
    char* wreg = ws + W_OFF;
    f16* tQKV  = (f16*)(wreg);
    f16* tWoT  = (f16*)(wreg + 3538944);
    f16* sQKV  = (f16*)(wreg + 4718592);
    f16* sWoT  = (f16*)(wreg + 8257536);
    f16* W1T   = (f16*)(wreg + 9437184);
    f16* W2T   = (f16*)(wreg + 14155776);
    float* tBias = (float*)(wreg + 18874368);
    float* sBias = (float*)(wreg + 18883584);
    float* xcur  = (float*)d_out;

    dim3 tb(256);
    // --- weight prep ---
    transpose_kernel<<<dim3(24, 24), tb, 0, stream>>>(t_Wq, tQKV, 768, 768);
    transpose_kernel<<<dim3(24, 24), tb, 0, stream>>>(t_Wk, tQKV + 768 * 768, 768, 768);
    transpose_kernel<<<dim3(24, 24), tb, 0, stream>>>(t_Wv, tQKV + 2 * 768 * 768, 768, 768);
    transpose_kernel<<<dim3(24, 24), tb, 0, stream>>>(t_Wo, tWoT, 768, 768);
    transpose_kernel<<<dim3(24, 24), tb, 0, stream>>>(s_Wq, sQKV, 768, 768);
    transpose_kernel<<<dim3(24, 24), tb, 0, stream>>>(s_Wk, sQKV + 768 * 768, 768, 768);
    transpose_kernel<<<dim3(24, 24), tb, 0, stream>>>(s_Wv, sQKV + 2 * 768 * 768, 768, 768);
    transpose_kernel<<<dim3(24, 24), tb, 0, stream>>>(s_Wo, sWoT, 768, 768);
    transpose_kernel<<<dim3(96, 24), tb, 0, stream>>>(W1, W1T, 768, 3072);
    transpose_kernel<<<dim3(24, 96), tb, 0, stream>>>(W2, W2T, 3072, 768);
    bias3_kernel<<<3, tb, 0, stream>>>(t_bq, t_bk, t_bv, tBias);
    bias3_kernel<<<3, tb, 0, stream>>>(s_bq, s_bk, s_bv, sBias);

    // --- phase A: time MHA ---
    ln_kernel<<<3138, tb, 0, stream>>>(x_in, ln1g, ln1b, y);
    gemm_kernel<QKVN, false, false, true><<<MB_PAD * 18, tb, 0, stream>>>(y, tQKV, tBias, nullptr, nullptr, qkv, 768);
    time_attn_kernel<<<4704, tb, 0, stream>>>(qkv, ctx);
    cls_part_kernel<<<BQ * NH * CCH, tb, 0, stream>>>(qkv, clsP);
    cls_comb_kernel<<<24, tb, 0, stream>>>(clsP, ctx);
    gemm_kernel<DM, false, true, false><<<MB_PAD * 6, tb, 0, stream>>>(ctx, tWoT, t_bo, x_in, xcur, nullptr, 768);

    // --- phase B: space MHA ---
    ln_kernel<<<3138, tb, 0, stream>>>(xcur, ln2g, ln2b, y);
    gemm_kernel<QKVN, false, false, true><<<MB_PAD * 18, tb, 0, stream>>>(y, sQKV, sBias, nullptr, nullptr, qkv, 768);
    space_attn_kernel<<<768, tb, 0, stream>>>(qkv, ctx);
    cls_part_kernel<<<BQ * NH * CCH, tb, 0, stream>>>(qkv, clsP);
    cls_comb_kernel<<<24, tb, 0, stream>>>(clsP, ctx);
    gemm_kernel<DM, false, true, false><<<MB_PAD * 6, tb, 0, stream>>>(ctx, sWoT, s_bo, xcur, xcur, nullptr, 768);

    // --- phase C: MLP ---
    ln_kernel<<<3138, tb, 0, stream>>>(xcur, ln3g, ln3b, y);
    gemm_kernel<D4, true, false, true><<<MB_PAD * 24, tb, 0, stream>>>(y, W1T, b1, nullptr, nullptr, hbuf, 768);
    gemm_kernel<DM, false, true, false><<<MB_PAD * 6, tb, 0, stream>>>(hbuf, W2T, b2, xcur, xcur, nullptr, 3072);
}

// Round 7
// 867.907 us; speedup vs baseline: 1.2560x; 1.0388x over previous
//
#include <hip/hip_runtime.h>

// ---------------- problem constants ----------------
#define BQ   8
#define SQ   1569
#define BS   12552      // BQ*SQ
#define DM   768
#define NH   12
#define DH   64
#define TT   8
#define PP   196
#define D4   3072
#define QKVN 2304
#define CCH  24         // CLS split-K chunks
#define CKEY 66         // keys per chunk (24*66 = 1584 >= 1569)
#define MB_PAD 104      // 99 m-blocks padded to multiple of 8 for XCD-stable swizzle

typedef _Float16 f16;
typedef _Float16 f16x8 __attribute__((ext_vector_type(8)));
typedef float    f32x4 __attribute__((ext_vector_type(4)));
typedef unsigned long long u64;

#define AS1 __attribute__((address_space(1)))
#define AS3 __attribute__((address_space(3)))

#define Y_OFF    0ULL
#define QKV_OFF  19279872ULL
#define CTX_OFF  77119488ULL
#define H_OFF    19279872ULL
#define W_OFF    96399360ULL

// ---------------- LayerNorm (wave per row) ----------------
__global__ __launch_bounds__(256) void ln_kernel(const float* __restrict__ x,
                                                 const float* __restrict__ g,
                                                 const float* __restrict__ bta,
                                                 f16* __restrict__ y) {
    int row = blockIdx.x * 4 + (threadIdx.x >> 6);
    int lane = threadIdx.x & 63;
    if (row >= BS) return;
    const float* xr = x + (u64)row * DM;
    float v[12];
    float s = 0.f, s2 = 0.f;
#pragma unroll
    for (int i = 0; i < 12; i++) { v[i] = xr[lane + i * 64]; s += v[i]; s2 += v[i] * v[i]; }
#pragma unroll
    for (int m = 1; m < 64; m <<= 1) { s += __shfl_xor(s, m, 64); s2 += __shfl_xor(s2, m, 64); }
    float mean = s * (1.f / 768.f);
    float var  = s2 * (1.f / 768.f) - mean * mean;
    float rstd = rsqrtf(var + 1e-12f);
    f16* yr = y + (u64)row * DM;
#pragma unroll
    for (int i = 0; i < 12; i++) {
        int c = lane + i * 64;
        yr[c] = (f16)((v[i] - mean) * rstd * g[c] + bta[c]);
    }
}

// ---------------- transpose fp32 -> f16 (dst[c*R+r] = src[r*C+c]) ----------------
__global__ __launch_bounds__(256) void transpose_kernel(const float* __restrict__ src,
                                                        f16* __restrict__ dst,
                                                        int R, int C) {
    __shared__ float tile[32][33];
    int bx = blockIdx.x * 32;
    int by = blockIdx.y * 32;
    int tx = threadIdx.x & 31, ty = threadIdx.x >> 5;
#pragma unroll
    for (int i = 0; i < 4; i++) {
        int r = by + ty + i * 8, c = bx + tx;
        if (r < R && c < C) tile[ty + i * 8][tx] = src[(u64)r * C + c];
    }
    __syncthreads();
#pragma unroll
    for (int i = 0; i < 4; i++) {
        int c = bx + ty + i * 8, r = by + tx;
        if (c < C && r < R) dst[(u64)c * R + r] = (f16)tile[tx][ty + i * 8];
    }
}

// ---------------- concat 3 bias vectors (768 each) ----------------
__global__ __launch_bounds__(256) void bias3_kernel(const float* __restrict__ a,
                                                    const float* __restrict__ b,
                                                    const float* __restrict__ c,
                                                    float* __restrict__ dst) {
    int i = blockIdx.x * 256 + threadIdx.x;
    if (i < 768) { dst[i] = a[i]; dst[i + 768] = b[i]; dst[i + 1536] = c[i]; }
}

// ---------------- GEMM v5: R4 staging + 1-barrier dbuf + 4-wave occupancy ----------------
// C = A(BSxK,f16) @ Bt^T (Bt NxK f16) + bias [+gelu][+resid]
// Grid: id = nb*MB_PAD + mb (mb fastest -> id%8 == mb%8, XCD-stable A slices).
// __launch_bounds__(256,4): cap unified VGPR+AGPR at 128/wave -> 4 waves/SIMD.
template <int NOUT, bool GELU, bool RESID, bool OUTF16>
__global__ __launch_bounds__(256, 4) void gemm_kernel(const f16* __restrict__ A,
                                                      const f16* __restrict__ Bt,
                                                      const float* __restrict__ bias,
                                                      const float* __restrict__ resid,
                                                      float* __restrict__ Cf,
                                                      f16* __restrict__ Ch,
                                                      int K) {
    __shared__ __align__(16) f16 As[2][128 * 32];
    __shared__ __align__(16) f16 Bs[2][128 * 32];
    int id = blockIdx.x;
    int mb = id % MB_PAD, nb = id / MB_PAD;
    if (mb >= 99) return;
    int tid  = threadIdx.x;
    int lane = tid & 63, wave = tid >> 6;
    int wm = wave >> 1, wn = wave & 1;
    int m0 = mb * 128, n0 = nb * 128;
    int l15 = lane & 15, quad = lane >> 4;

    // staging addressing (R4): wave w stages rows w*16+(lane>>2) (+64 for half 1),
    // 8-f16 chunk (lane&3); LDS byte = wave*1024 + lane*16 (+4096)
    int r0   = wave * 16 + (lane >> 2);
    int coff = (lane & 3) * 8;
    const f16* ag0 = A + (u64)(m0 + r0) * K + coff;
    const f16* ag1 = A + (u64)(m0 + r0 + 64) * K + coff;
    bool av0 = (m0 + r0) < BS, av1 = (m0 + r0 + 64) < BS;
    const f16* bg0 = Bt + (u64)(n0 + r0) * K + coff;
    const f16* bg1 = Bt + (u64)(n0 + r0 + 64) * K + coff;
    int lofs = wave * 1024;

    f32x4 acc[4][4];
#pragma unroll
    for (int i = 0; i < 4; i++)
#pragma unroll
        for (int j = 0; j < 4; j++)
#pragma unroll
            for (int r = 0; r < 4; r++) acc[i][j][r] = 0.f;

    // prologue: stage tile 0 into buffer 0
    if (av0) __builtin_amdgcn_global_load_lds((const AS1 void*)ag0, (AS3 void*)((AS3 char*)&As[0][0] + lofs), 16, 0, 0);
    if (av1) __builtin_amdgcn_global_load_lds((const AS1 void*)ag1, (AS3 void*)((AS3 char*)&As[0][0] + lofs + 4096), 16, 0, 0);
    __builtin_amdgcn_global_load_lds((const AS1 void*)bg0, (AS3 void*)((AS3 char*)&Bs[0][0] + lofs), 16, 0, 0);
    __builtin_amdgcn_global_load_lds((const AS1 void*)bg1, (AS3 void*)((AS3 char*)&Bs[0][0] + lofs + 4096), 16, 0, 0);
    ag0 += 32; ag1 += 32; bg0 += 32; bg1 += 32;

    int nit = K >> 5;
    for (int it = 0; it < nit; it++) {
        __syncthreads();                 // drains staging for buffer it&1
        int buf = it & 1;
        if (it + 1 < nit) {              // prefetch next tile into other buffer
            int nb2 = buf ^ 1;
            if (av0) __builtin_amdgcn_global_load_lds((const AS1 void*)ag0, (AS3 void*)((AS3 char*)&As[nb2][0] + lofs), 16, 0, 0);
            if (av1) __builtin_amdgcn_global_load_lds((const AS1 void*)ag1, (AS3 void*)((AS3 char*)&As[nb2][0] + lofs + 4096), 16, 0, 0);
            __builtin_amdgcn_global_load_lds((const AS1 void*)bg0, (AS3 void*)((AS3 char*)&Bs[nb2][0] + lofs), 16, 0, 0);
            __builtin_amdgcn_global_load_lds((const AS1 void*)bg1, (AS3 void*)((AS3 char*)&Bs[nb2][0] + lofs + 4096), 16, 0, 0);
            ag0 += 32; ag1 += 32; bg0 += 32; bg1 += 32;
        }
        f16x8 af[4], bf[4];
#pragma unroll
        for (int i = 0; i < 4; i++)
            af[i] = *(const f16x8*)(&As[buf][(wm * 64 + i * 16 + l15) * 32 + quad * 8]);
#pragma unroll
        for (int j = 0; j < 4; j++)
            bf[j] = *(const f16x8*)(&Bs[buf][(wn * 64 + j * 16 + l15) * 32 + quad * 8]);
#pragma unroll
        for (int i = 0; i < 4; i++)
#pragma unroll
            for (int j = 0; j < 4; j++)
                acc[i][j] = __builtin_amdgcn_mfma_f32_16x16x32_f16(af[i], bf[j], acc[i][j], 0, 0, 0);
    }

#pragma unroll
    for (int i = 0; i < 4; i++) {
#pragma unroll
        for (int j = 0; j < 4; j++) {
            int col = n0 + wn * 64 + j * 16 + l15;
            float bv = bias[col];
#pragma unroll
            for (int r = 0; r < 4; r++) {
                int row = m0 + wm * 64 + i * 16 + quad * 4 + r;
                if (row < BS) {
                    float v = acc[i][j][r] + bv;
                    if (GELU) {
                        // tanh-approx GELU (max dev ~3e-3 from exact erf form):
                        // gelu(x) = x * sigmoid(2*0.7978845608*(x + 0.044715 x^3))
                        float u = 0.7978845608028654f * (v + 0.044715f * v * v * v);
                        float e = __builtin_exp2f(-2.885390081777927f * u);
                        v = v / (1.f + e);
                    }
                    if (RESID) v += resid[(u64)row * NOUT + col];
                    if (OUTF16) Ch[(u64)row * NOUT + col] = (f16)v;
                    else        Cf[(u64)row * NOUT + col] = v;
                }
            }
        }
    }
}

// ---------------- time attention: wave per (b,h,p); 8 queries x 9 keys ----------------
__global__ __launch_bounds__(256) void time_attn_kernel(const f16* __restrict__ qkv,
                                                        f16* __restrict__ ctx) {
    int w = blockIdx.x * 4 + (threadIdx.x >> 6);
    int lane = threadIdx.x & 63;
    int b = w / (NH * PP);
    int rem = w % (NH * PP);
    int h = rem / PP, p = rem % PP;
    u64 bb = (u64)b * SQ;
    int hoff = h * 64 + lane;

    float qv[TT], kv[9], vv[9];
#pragma unroll
    for (int t = 0; t < TT; t++) qv[t] = (float)qkv[(bb + 1 + t * PP + p) * QKVN + hoff];
    kv[0] = (float)qkv[bb * QKVN + 768 + hoff];
    vv[0] = (float)qkv[bb * QKVN + 1536 + hoff];
#pragma unroll
    for (int j = 1; j <= TT; j++) {
        u64 ro = (bb + 1 + (u64)(j - 1) * PP + p) * QKVN;
        kv[j] = (float)qkv[ro + 768 + hoff];
        vv[j] = (float)qkv[ro + 1536 + hoff];
    }
#pragma unroll
    for (int t = 0; t < TT; t++) {
        float s[9];
#pragma unroll
        for (int j = 0; j < 9; j++) {
            float ps = qv[t] * kv[j];
#pragma unroll
            for (int m = 1; m < 64; m <<= 1) ps += __shfl_xor(ps, m, 64);
            s[j] = ps * 0.125f;
        }
        float mx = s[0];
#pragma unroll
        for (int j = 1; j < 9; j++) mx = fmaxf(mx, s[j]);
        float sum = 0.f;
#pragma unroll
        for (int j = 0; j < 9; j++) { s[j] = expf(s[j] - mx); sum += s[j]; }
        float o = 0.f;
#pragma unroll
        for (int j = 0; j < 9; j++) o += s[j] * vv[j];
        o /= sum;
        ctx[(bb + 1 + (u64)t * PP + p) * DM + h * 64 + lane] = (f16)o;
    }
}

// ---------------- CLS attention split-K: part kernel, block per (b,h,chunk) ----------------
__global__ __launch_bounds__(256) void cls_part_kernel(const f16* __restrict__ qkv,
                                                       float* __restrict__ part) {
    int g = blockIdx.x;
    int c = g % CCH, bh = g / CCH;
    int b = bh / NH, h = bh % NH;
    u64 bb = (u64)b * SQ;
    int tid = threadIdx.x, lane = tid & 63, wave = tid >> 6;
    __shared__ float sc[CKEY];
    __shared__ float accbuf[4][64];
    __shared__ float lbuf[4];
    __shared__ float mxs;
    float qd = (float)qkv[bb * QKVN + h * 64 + lane];
    int j0 = c * CKEY;
    int cnt = SQ - j0; if (cnt > CKEY) cnt = CKEY;
    for (int jj = wave; jj < cnt; jj += 4) {
        float p = qd * (float)qkv[(bb + j0 + jj) * QKVN + 768 + h * 64 + lane];
#pragma unroll
        for (int m = 1; m < 64; m <<= 1) p += __shfl_xor(p, m, 64);
        if (lane == 0) sc[jj] = p * 0.125f;
    }
    __syncthreads();
    if (wave == 0) {
        float m = -1e30f;
        for (int j = lane; j < cnt; j += 64) m = fmaxf(m, sc[j]);
#pragma unroll
        for (int s = 1; s < 64; s <<= 1) m = fmaxf(m, __shfl_xor(m, s, 64));
        if (lane == 0) mxs = m;
    }
    __syncthreads();
    float mx = mxs;
    float acc = 0.f, l = 0.f;
    for (int jj = wave; jj < cnt; jj += 4) {
        float w = expf(sc[jj] - mx);
        l += w;
        acc += w * (float)qkv[(bb + j0 + jj) * QKVN + 1536 + h * 64 + lane];
    }
    accbuf[wave][lane] = acc;
    if (lane == 0) lbuf[wave] = l;
    __syncthreads();
    if (tid < 64) {
        float a = accbuf[0][tid] + accbuf[1][tid] + accbuf[2][tid] + accbuf[3][tid];
        float* pb = part + ((u64)bh * CCH + c) * 66;
        if (tid == 0) { pb[0] = mxs; pb[1] = lbuf[0] + lbuf[1] + lbuf[2] + lbuf[3]; }
        pb[2 + tid] = a;
    }
}

// ---------------- CLS attention split-K: combine kernel, wave per (b,h) ----------------
__global__ __launch_bounds__(256) void cls_comb_kernel(const float* __restrict__ part,
                                                       f16* __restrict__ ctx) {
    int w = blockIdx.x * 4 + (threadIdx.x >> 6);
    int lane = threadIdx.x & 63;
    if (w >= BQ * NH) return;
    int b = w / NH, h = w % NH;
    const float* pb = part + (u64)w * CCH * 66;
    float m = (lane < CCH) ? pb[lane * 66] : -1e30f;
#pragma unroll
    for (int s = 1; s < 64; s <<= 1) m = fmaxf(m, __shfl_xor(m, s, 64));
    float l = (lane < CCH) ? pb[lane * 66 + 1] * expf(pb[lane * 66] - m) : 0.f;
#pragma unroll
    for (int s = 1; s < 64; s <<= 1) l += __shfl_xor(l, s, 64);
    float o = 0.f;
    for (int j = 0; j < CCH; j++) {
        float mj = pb[j * 66];
        o += pb[j * 66 + 2 + lane] * expf(mj - m);
    }
    ctx[((u64)b * SQ) * DM + h * 64 + lane] = (f16)(o / l);
}

// ---------------- space attention: MFMA flash, block per (b,h,t) ----------------
__global__ __launch_bounds__(256) void space_attn_kernel(const f16* __restrict__ qkv,
                                                         f16* __restrict__ ctx) {
    int g = blockIdx.x;
    int b = g / (NH * TT);
    int rem = g % (NH * TT);
    int h = rem / TT, t = rem % TT;
    __shared__ __align__(16) f16 Vt[64 * 232];
    __shared__ __align__(16) f16 Ps[4 * 16 * 232];
    u64 bb = (u64)b * SQ;
    int tid = threadIdx.x, lane = tid & 63, wave = tid >> 6;
    int l15 = lane & 15, quad = lane >> 4;

    for (int i = tid; i < 4 * 16 * 232 * 2 / 16; i += 256)
        ((uint4*)Ps)[i] = make_uint4(0u, 0u, 0u, 0u);

    for (int idx = tid; idx < 232 * 8; idx += 256) {
        int c8 = idx / 232;
        int j  = idx - c8 * 232;
        int c  = c8 * 8;
        uint4 vraw = make_uint4(0u, 0u, 0u, 0u);
        if (j < 197) {
            int tok = (j == 0) ? 0 : (1 + t * PP + (j - 1));
            vraw = *(const uint4*)(qkv + (bb + tok) * QKVN + 1536 + h * 64 + c);
        }
        f16x8 vv = *(f16x8*)&vraw;
#pragma unroll
        for (int e = 0; e < 8; e++) Vt[(c + e) * 232 + j] = vv[e];
    }
    __syncthreads();

    f16* myP = Ps + wave * 16 * 232;
    for (int qt = wave; qt < 13; qt += 4) {
        int mloc = qt * 16 + l15;
        int mc = mloc > 195 ? 195 : mloc;
        const f16* qr = qkv + (bb + 1 + (u64)t * PP + mc) * QKVN + h * 64;
        f16x8 qa0 = *(const f16x8*)(qr + quad * 8);
        f16x8 qa1 = *(const f16x8*)(qr + 32 + quad * 8);

        f32x4 s[13];
#pragma unroll
        for (int nt = 0; nt < 13; nt++) { s[nt][0] = 0.f; s[nt][1] = 0.f; s[nt][2] = 0.f; s[nt][3] = 0.f; }
#pragma unroll
        for (int nt = 0; nt < 13; nt++) {
            int n = nt * 16 + l15;
            int ncl = n > 196 ? 196 : n;
            int tok = (ncl == 0) ? 0 : (1 + t * PP + (ncl - 1));
            const f16* kr = qkv + (bb + tok) * QKVN + 768 + h * 64;
            f16x8 kb0 = *(const f16x8*)(kr + quad * 8);
            f16x8 kb1 = *(const f16x8*)(kr + 32 + quad * 8);
            s[nt] = __builtin_amdgcn_mfma_f32_16x16x32_f16(qa0, kb0, s[nt], 0, 0, 0);
            s[nt] = __builtin_amdgcn_mfma_f32_16x16x32_f16(qa1, kb1, s[nt], 0, 0, 0);
        }
        if (l15 >= 5) { s[12][0] = -1e30f; s[12][1] = -1e30f; s[12][2] = -1e30f; s[12][3] = -1e30f; }

        float mx[4] = {-1e30f, -1e30f, -1e30f, -1e30f};
#pragma unroll
        for (int nt = 0; nt < 13; nt++)
#pragma unroll
            for (int r = 0; r < 4; r++) mx[r] = fmaxf(mx[r], s[nt][r]);
#pragma unroll
        for (int m = 1; m < 16; m <<= 1)
#pragma unroll
            for (int r = 0; r < 4; r++) mx[r] = fmaxf(mx[r], __shfl_xor(mx[r], m, 64));

        float sum[4] = {0.f, 0.f, 0.f, 0.f};
#pragma unroll
        for (int nt = 0; nt < 13; nt++)
#pragma unroll
            for (int r = 0; r < 4; r++) {
                float p = exp2f((s[nt][r] - mx[r]) * 0.18033688011112042f);
                s[nt][r] = p;
                sum[r] += p;
            }
#pragma unroll
        for (int m = 1; m < 16; m <<= 1)
#pragma unroll
            for (int r = 0; r < 4; r++) sum[r] += __shfl_xor(sum[r], m, 64);

#pragma unroll
        for (int nt = 0; nt < 13; nt++)
#pragma unroll
            for (int r = 0; r < 4; r++)
                myP[(quad * 4 + r) * 232 + nt * 16 + l15] = (f16)s[nt][r];

        f32x4 o[4];
#pragma unroll
        for (int n2 = 0; n2 < 4; n2++) { o[n2][0] = 0.f; o[n2][1] = 0.f; o[n2][2] = 0.f; o[n2][3] = 0.f; }
#pragma unroll
        for (int kc = 0; kc < 7; kc++) {
            f16x8 pa = *(const f16x8*)(&myP[l15 * 232 + kc * 32 + quad * 8]);
#pragma unroll
            for (int n2 = 0; n2 < 4; n2++) {
                f16x8 vb = *(const f16x8*)(&Vt[(n2 * 16 + l15) * 232 + kc * 32 + quad * 8]);
                o[n2] = __builtin_amdgcn_mfma_f32_16x16x32_f16(pa, vb, o[n2], 0, 0, 0);
            }
        }

        float inv[4];
#pragma unroll
        for (int r = 0; r < 4; r++) inv[r] = 1.f / sum[r];
#pragma unroll
        for (int n2 = 0; n2 < 4; n2++)
#pragma unroll
            for (int r = 0; r < 4; r++) {
                int m = qt * 16 + quad * 4 + r;
                if (m < PP)
                    ctx[(bb + 1 + (u64)t * PP + m) * DM + h * 64 + n2 * 16 + l15] = (f16)(o[n2][r] * inv[r]);
            }
    }
}

// ---------------- host ----------------
extern "C" void kernel_launch(void* const* d_in, const int* in_sizes, int n_in,
                              void* d_out, int out_size, void* d_ws, size_t ws_size,
                              hipStream_t stream) {
    const float* x_in  = (const float*)d_in[0];
    const float* t_Wq  = (const float*)d_in[1];
    const float* t_bq  = (const float*)d_in[2];
    const float* t_Wk  = (const float*)d_in[3];
    const float* t_bk  = (const float*)d_in[4];
    const float* t_Wv  = (const float*)d_in[5];
    const float* t_bv  = (const float*)d_in[6];
    const float* t_Wo  = (const float*)d_in[7];
    const float* t_bo  = (const float*)d_in[8];
    const float* s_Wq  = (const float*)d_in[9];
    const float* s_bq  = (const float*)d_in[10];
    const float* s_Wk  = (const float*)d_in[11];
    const float* s_bk  = (const float*)d_in[12];
    const float* s_Wv  = (const float*)d_in[13];
    const float* s_bv  = (const float*)d_in[14];
    const float* s_Wo  = (const float*)d_in[15];
    const float* s_bo  = (const float*)d_in[16];
    const float* W1    = (const float*)d_in[17];
    const float* b1    = (const float*)d_in[18];
    const float* W2    = (const float*)d_in[19];
    const float* b2    = (const float*)d_in[20];
    const float* ln1g  = (const float*)d_in[21];
    const float* ln1b  = (const float*)d_in[22];
    const float* ln2g  = (const float*)d_in[23];
    const float* ln2b  = (const float*)d_in[24];
    const float* ln3g  = (const float*)d_in[25];
    const float* ln3b  = (const float*)d_in[26];

    char* ws = (char*)d_ws;
    f16* y    = (f16*)(ws + Y_OFF);
    f16* qkv  = (f16*)(ws + QKV_OFF);
    f16* ctx  = (f16*)(ws + CTX_OFF);
    f16* hbuf = (f16*)(ws + H_OFF);
    float* clsP = (float*)(ws + Y_OFF);   // reuses dead y region
    char* wreg = ws + W_OFF;
    f16* tQKV  = (f16*)(wreg);
    f16* tWoT  = (f16*)(wreg + 3538944);
    f16* sQKV  = (f16*)(wreg + 4718592);
    f16* sWoT  = (f16*)(wreg + 8257536);
    f16* W1T   = (f16*)(wreg + 9437184);
    f16* W2T   = (f16*)(wreg + 14155776);
    float* tBias = (float*)(wreg + 18874368);
    float* sBias = (float*)(wreg + 18883584);
    float* xcur  = (float*)d_out;

    dim3 tb(256);
    // --- weight prep ---
    transpose_kernel<<<dim3(24, 24), tb, 0, stream>>>(t_Wq, tQKV, 768, 768);
    transpose_kernel<<<dim3(24, 24), tb, 0, stream>>>(t_Wk, tQKV + 768 * 768, 768, 768);
    transpose_kernel<<<dim3(24, 24), tb, 0, stream>>>(t_Wv, tQKV + 2 * 768 * 768, 768, 768);
    transpose_kernel<<<dim3(24, 24), tb, 0, stream>>>(t_Wo, tWoT, 768, 768);
    transpose_kernel<<<dim3(24, 24), tb, 0, stream>>>(s_Wq, sQKV, 768, 768);
    transpose_kernel<<<dim3(24, 24), tb, 0, stream>>>(s_Wk, sQKV + 768 * 768, 768, 768);
    transpose_kernel<<<dim3(24, 24), tb, 0, stream>>>(s_Wv, sQKV + 2 * 768 * 768, 768, 768);
    transpose_kernel<<<dim3(24, 24), tb, 0, stream>>>(s_Wo, sWoT, 768, 768);
    transpose_kernel<<<dim3(96, 24), tb, 0, stream>>>(W1, W1T, 768, 3072);
    transpose_kernel<<<dim3(24, 96), tb, 0, stream>>>(W2, W2T, 3072, 768);
    bias3_kernel<<<3, tb, 0, stream>>>(t_bq, t_bk, t_bv, tBias);
    bias3_kernel<<<3, tb, 0, stream>>>(s_bq, s_bk, s_bv, sBias);

    // --- phase A: time MHA ---
    ln_kernel<<<3138, tb, 0, stream>>>(x_in, ln1g, ln1b, y);
    gemm_kernel<QKVN, false, false, true><<<MB_PAD * 18, tb, 0, stream>>>(y, tQKV, tBias, nullptr, nullptr, qkv, 768);
    time_attn_kernel<<<4704, tb, 0, stream>>>(qkv, ctx);
    cls_part_kernel<<<BQ * NH * CCH, tb, 0, stream>>>(qkv, clsP);
    cls_comb_kernel<<<24, tb, 0, stream>>>(clsP, ctx);
    gemm_kernel<DM, false, true, false><<<MB_PAD * 6, tb, 0, stream>>>(ctx, tWoT, t_bo, x_in, xcur, nullptr, 768);

    // --- phase B: space MHA ---
    ln_kernel<<<3138, tb, 0, stream>>>(xcur, ln2g, ln2b, y);
    gemm_kernel<QKVN, false, false, true><<<MB_PAD * 18, tb, 0, stream>>>(y, sQKV, sBias, nullptr, nullptr, qkv, 768);
    space_attn_kernel<<<768, tb, 0, stream>>>(qkv, ctx);
    cls_part_kernel<<<BQ * NH * CCH, tb, 0, stream>>>(qkv, clsP);
    cls_comb_kernel<<<24, tb, 0, stream>>>(clsP, ctx);
    gemm_kernel<DM, false, true, false><<<MB_PAD * 6, tb, 0, stream>>>(ctx, sWoT, s_bo, xcur, xcur, nullptr, 768);

    // --- phase C: MLP ---
    ln_kernel<<<3138, tb, 0, stream>>>(xcur, ln3g, ln3b, y);
    gemm_kernel<D4, true, false, true><<<MB_PAD * 24, tb, 0, stream>>>(y, W1T, b1, nullptr, nullptr, hbuf, 768);
    gemm_kernel<DM, false, true, false><<<MB_PAD * 6, tb, 0, stream>>>(hbuf, W2T, b2, xcur, xcur, nullptr, 3072);
}